// Round 10
// baseline (245.413 us; speedup 1.0000x reference)
//
#include <hip/hip_runtime.h>
#include <math.h>

typedef __attribute__((ext_vector_type(8))) short bf16x8;
typedef __attribute__((ext_vector_type(16))) float f32x16;

#define Bsz 4
#define Nn 1024
#define TN 3072
#define Dd 256
#define Hh 4
#define DH 64
#define TAUc 1e-3f
#define QSCALE 0.1803368801111f   // log2(e)/8 : softmax done in exp2 domain

// workspace layout (float offsets)
#define SALP_OFF 0           // 98304 (4 b x 96 slabs x 256 d partial sums)
#define IDX_OFF  98304       // 256 ints
#define XCB_OFF  98560       // bf16 (4,3072,64) = 393216 floats
#define WCT_OFF  491776      // bf16 (4,3,256,64) = 98304 floats
#define QB_OFF   590080      // bf16 (16,3072,64) linear
#define KB_OFF   2162944     // bf16 swizzled tiles (16 bh,24 tiles,8192)
#define VT_OFF   3735808     // bf16 swizzled tiles (16 bh,24 tiles,8192)
#define OP_OFF   5308672     // fp32 (4,3072,256) attention out (atomic-summed)
#define SML_OFF  8454400     // float [16][3072] row sums l (atomic-summed)

__device__ __forceinline__ ushort f2b(float f) {
    uint u = __float_as_uint(f);
    u += 0x7fffu + ((u >> 16) & 1u);
    return (ushort)(u >> 16);
}
__device__ __forceinline__ uint pk2(float a, float b) {   // RNE pack (software)
    return (uint)f2b(a) | ((uint)f2b(b) << 16);
}
__device__ __forceinline__ uint trunc_pk(float a, float b) {
    return (__float_as_uint(a) >> 16) | (__float_as_uint(b) & 0xFFFF0000u);
}
__device__ __forceinline__ float hi_f(float a) {
    return __uint_as_float(__float_as_uint(a) & 0xFFFF0000u);
}
__device__ __forceinline__ uint cvtpk(float a, float b) {  // HW RNE pack
    uint r;
    asm("v_cvt_pk_bf16_f32 %0, %1, %2" : "=v"(r) : "v"(a), "v"(b));
    return r;
}
// async global->LDS DMA, 16B per lane (lane-linear LDS destination)
__device__ __forceinline__ void gld16(const ushort* g, ushort* l) {
    __builtin_amdgcn_global_load_lds(
        (const __attribute__((address_space(1))) uint*)g,
        (__attribute__((address_space(3))) uint*)l, 16, 0, 0);
}
union U4B8 { uint u[4]; bf16x8 v; };
__device__ __forceinline__ bf16x8 ld8(const ushort* p) { return *(const bf16x8*)p; }

// ---- kernel 1: per-channel saliency partial sums + zero-init of OP ----
__global__ __launch_bounds__(256) void k_sal(
        const float* __restrict__ F0, const float* __restrict__ F1,
        const float* __restrict__ F2, float* __restrict__ salp,
        float* __restrict__ OPz) {
    // zero the attention-output accumulator (atomic-add target for k_attn)
    {
        size_t zb = ((size_t)blockIdx.x * 256 + threadIdx.x) * 32;
        float4 z = {0.f, 0.f, 0.f, 0.f};
        #pragma unroll
        for (int i = 0; i < 8; ++i) *(float4*)&OPz[zb + i * 4] = z;
    }
    int b = blockIdx.x / 96;
    int slab = blockIdx.x - b * 96;
    int t0 = slab * 32;
    int seg = t0 >> 10, tt0 = t0 & 1023;
    const float* F = (seg == 0) ? F0 : (seg == 1 ? F1 : F2);
    const float* base = &F[(size_t)((b << 10) + tt0) * Dd + threadIdx.x];
    float acc = 0.f;
    #pragma unroll 4
    for (int r = 0; r < 32; ++r) {
        float x = base[(size_t)r * Dd];
        acc += fmaxf(fabsf(x) - TAUc, 0.f);
    }
    salp[blockIdx.x * 256 + threadIdx.x] = acc;
}

// ---- kernel 2: reduce partials + top-64 selection + zero-init of Sml ----
__global__ void k_topk(const float* __restrict__ salp, int* __restrict__ idx,
                       float* __restrict__ Smlz) {
    __shared__ float v[256];
    __shared__ int cnt;
    int b = blockIdx.x, tid = threadIdx.x;
    {
        int gid = b * 256 + tid;            // 1024 threads x 48 floats = 49152
        #pragma unroll
        for (int i = 0; i < 12; ++i) {
            float4 z = {0.f, 0.f, 0.f, 0.f};
            *(float4*)&Smlz[(size_t)gid * 48 + i * 4] = z;
        }
    }
    float myval = 0.f;
    const float* p = &salp[(size_t)b * 96 * 256 + tid];
    #pragma unroll 4
    for (int s = 0; s < 96; ++s) myval += p[s * 256];
    v[tid] = myval;
    if (tid == 0) cnt = 0;
    __syncthreads();
    for (int k = 2; k <= 256; k <<= 1)
        for (int j = k >> 1; j > 0; j >>= 1) {
            int ixj = tid ^ j;
            if (ixj > tid) {
                float a = v[tid], c = v[ixj];
                bool up = ((tid & k) == 0);
                if ((a > c) == up) { v[tid] = c; v[ixj] = a; }
            }
            __syncthreads();
        }
    float thr = v[192];
    if (myval >= thr) {
        int p2 = atomicAdd(&cnt, 1);
        if (p2 < 64) idx[b * 64 + p2] = tid;
    }
}

// ---- kernel 3: merged gathers (blocks 0..383: X; 384..767: W columns) ----
__global__ __launch_bounds__(256) void k_gather(
        const float* __restrict__ F0, const float* __restrict__ F1,
        const float* __restrict__ F2,
        const float* __restrict__ Wq, const float* __restrict__ Wk,
        const float* __restrict__ Wv, const int* __restrict__ idx,
        uint* __restrict__ Xcb, uint* __restrict__ Wct) {
    __shared__ float xs[32 * 260];
    __shared__ int ids[64];
    int tid = threadIdx.x;
    if (blockIdx.x < 384) {
        int b = blockIdx.x / 96;
        int t0 = (blockIdx.x - b * 96) * 32;
        if (tid < 64) ids[tid] = idx[b * 64 + tid];
        int seg = t0 >> 10, tt0 = t0 & 1023;
        const float* F = (seg == 0) ? F0 : (seg == 1 ? F1 : F2);
        const float* base = &F[(size_t)((b << 10) + tt0) * Dd];
        #pragma unroll
        for (int i = 0; i < 8; ++i) {
            int i0 = tid + i * 256;
            int r = i0 >> 6, c4 = (i0 & 63) << 2;
            float4 x = *(const float4*)&base[(size_t)r * Dd + c4];
            x.x = copysignf(fmaxf(fabsf(x.x) - TAUc, 0.f), x.x);
            x.y = copysignf(fmaxf(fabsf(x.y) - TAUc, 0.f), x.y);
            x.z = copysignf(fmaxf(fabsf(x.z) - TAUc, 0.f), x.z);
            x.w = copysignf(fmaxf(fabsf(x.w) - TAUc, 0.f), x.w);
            *(float4*)&xs[r * 260 + c4] = x;
        }
        __syncthreads();
        #pragma unroll
        for (int i = 0; i < 4; ++i) {
            int i0 = tid + i * 256;
            int r = i0 >> 5, jp = i0 & 31;
            float x0 = xs[r * 260 + ids[2 * jp]];
            float x1 = xs[r * 260 + ids[2 * jp + 1]];
            Xcb[(size_t)(b * TN + t0 + r) * 32 + jp] = pk2(x0, x1);
        }
    } else {
        int gid = (blockIdx.x - 384) * 256 + tid;   // 98304
        int b = gid / 24576;
        if (tid < 64) ids[tid] = idx[b * 64 + tid];
        __syncthreads();
        int rem = gid - b * 24576;
        int mat = rem / 8192;
        int rem2 = rem - mat * 8192;
        int dout = rem2 >> 5, jp = rem2 & 31;
        const float* Wm = (mat == 0) ? Wq : (mat == 1 ? Wk : Wv);
        float w0 = Wm[(size_t)dout * 256 + ids[2 * jp]];
        float w1 = Wm[(size_t)dout * 256 + ids[2 * jp + 1]];
        Wct[((size_t)(b * 3 + mat) * 256 + dout) * 32 + jp] = pk2(w0, w1);
    }
}

// ---- kernel 4: QKV projection, 32x32x16 MFMA, LDS-free (r9 version) ----
__global__ __launch_bounds__(256) void k_qkv(
        const ushort* __restrict__ Xcb, const ushort* __restrict__ Wct,
        const float* __restrict__ bq, const float* __restrict__ bk,
        const float* __restrict__ bv,
        ushort* __restrict__ Qh, ushort* __restrict__ Kh, ushort* __restrict__ Vt) {
    int wave = threadIdx.x >> 6, lane = threadIdx.x & 63;
    int l31 = lane & 31, h = lane >> 5;
    int W = blockIdx.x * 4 + wave;          // 2304 wave-tasks
    int b = W / 576;
    int r = W - b * 576;
    int mat = r / 192;
    int p = r - mat * 192;
    const ushort* Xb = Xcb + (size_t)b * TN * 64;
    const ushort* Wm = Wct + (size_t)(b * 3 + mat) * 256 * 64;
    f32x16 c[4];
    #pragma unroll
    for (int nt = 0; nt < 4; ++nt)
        #pragma unroll
        for (int q = 0; q < 16; ++q) c[nt][q] = 0.f;
    if (mat < 2) {
        int mtt = p % 96, ng = p / 96;      // t tile, dout half
        const ushort* arow = &Xb[(size_t)(mtt * 32 + l31) * 64];
        #pragma unroll
        for (int kc = 0; kc < 4; ++kc) {
            bf16x8 af = ld8(arow + kc * 16 + 8 * h);
            #pragma unroll
            for (int nt = 0; nt < 4; ++nt) {
                bf16x8 bf = ld8(&Wm[(size_t)(ng * 128 + nt * 32 + l31) * 64 + kc * 16 + 8 * h]);
                c[nt] = __builtin_amdgcn_mfma_f32_32x32x16_bf16(af, bf, c[nt], 0, 0, 0);
            }
        }
        if (mat == 0) {
            #pragma unroll
            for (int nt = 0; nt < 4; ++nt) {
                int dout = ng * 128 + nt * 32 + l31;
                int head = dout >> 6, d63 = dout & 63;
                float bb = bq[dout];
                size_t obase = ((size_t)(b * 4 + head) * TN + mtt * 32) * 64 + d63;
                #pragma unroll
                for (int u = 0; u < 16; ++u) {
                    int trow = (u & 3) + 8 * (u >> 2) + 4 * h;
                    Qh[obase + (size_t)trow * 64] = f2b((c[nt][u] + bb) * QSCALE);
                }
            }
        } else {
            // K: swizzled tile: [bh][tile=t>>7][row=t&127][chunk=(d>>3)^fk][d&7]
            #pragma unroll
            for (int nt = 0; nt < 4; ++nt) {
                int dout = ng * 128 + nt * 32 + l31;
                int head = dout >> 6, d63 = dout & 63;
                float bb = bk[dout];
                size_t base = (size_t)(b * 4 + head) * 196608;
                #pragma unroll
                for (int u = 0; u < 16; ++u) {
                    int trow = (u & 3) + 8 * (u >> 2) + 4 * h;
                    int t = mtt * 32 + trow;
                    int row = t & 127, tile = t >> 7;
                    int fk = (row ^ (row >> 3)) & 7;
                    Kh[base + (size_t)tile * 8192 + row * 64 +
                       (((d63 >> 3) ^ fk) << 3) + (d63 & 7)] = f2b(c[nt][u] + bb);
                }
            }
        }
    } else {
        int mtv = p & 7, tg = p >> 3;       // dout tile (8), t group (24 = key tile)
        const ushort* arow = &Wm[(size_t)(mtv * 32 + l31) * 64];
        #pragma unroll
        for (int kc = 0; kc < 4; ++kc) {
            bf16x8 af = ld8(arow + kc * 16 + 8 * h);
            #pragma unroll
            for (int nt = 0; nt < 4; ++nt) {
                bf16x8 bf = ld8(&Xb[(size_t)(tg * 128 + nt * 32 + l31) * 64 + kc * 16 + 8 * h]);
                c[nt] = __builtin_amdgcn_mfma_f32_32x32x16_bf16(af, bf, c[nt], 0, 0, 0);
            }
        }
        int head = mtv >> 1;
        int sl = (l31 & 19) | ((l31 & 4) << 1) | ((l31 & 8) >> 1);  // swap bits 2<->3
        size_t vbase = (size_t)(b * 4 + head) * 196608 + (size_t)tg * 8192;
        // V: swizzled tile: [bh][tile=tg][row=d&63][chunk'=(c&8)|((c&7)^fv)][key&7]
        #pragma unroll
        for (int nt = 0; nt < 4; ++nt) {
            int cc = (nt * 32 + sl) >> 3;
            int elem = sl & 7;
            #pragma unroll
            for (int u = 0; u < 16; ++u) {
                int dout = mtv * 32 + (u & 3) + 8 * (u >> 2) + 4 * h;
                int row = dout & 63;
                int fv = (row ^ (row >> 3)) & 7;
                int ch = (cc & 8) | ((cc & 7) ^ fv);
                Vt[vbase + row * 128 + ch * 8 + elem] = f2b(c[nt][u] + bv[dout]);
            }
        }
    }
}

// ---- kernel 5: flash attention, split-K x4, atomic combine, MFMA row-sum ----
// Compute structure (fragments, swizzles, DMA staging, register-P) identical
// to r9; per-block key range is a quarter (6 stages); partial O and l are
// accumulated with native fp32 atomics (valid: no online max, pure sums).
__global__ __launch_bounds__(256, 4) void k_attn(
        const ushort* __restrict__ Qg, const ushort* __restrict__ Kg,
        const ushort* __restrict__ Vtg,
        float* __restrict__ OP, float* __restrict__ Sml) {
    __shared__ __align__(16) ushort Ks[128 * 64];    // keys x d (swizzled image)
    __shared__ __align__(16) ushort Vts[64 * 128];   // d x keys (swizzled image)
    int bh = blockIdx.x / 96;
    int rem = blockIdx.x - bh * 96;
    int qt = rem >> 2, ks = rem & 3;
    int b = bh >> 2, hh = bh & 3;
    int tid = threadIdx.x, wave = tid >> 6, lane = tid & 63;
    int l31 = lane & 31, h = lane >> 5;
    int q0 = qt * 128 + wave * 32;
    const ushort* Qb = Qg + ((size_t)bh * TN + q0 + l31) * DH;
    bf16x8 qf[4];
    #pragma unroll
    for (int kc = 0; kc < 4; ++kc) qf[kc] = ld8(&Qb[kc * 16 + 8 * h]);

    const ushort* Kt = Kg + (size_t)bh * 196608 + (size_t)(ks * 6) * 8192 + tid * 8;
    const ushort* Vtt = Vtg + (size_t)bh * 196608 + (size_t)(ks * 6) * 8192 + tid * 8;

    f32x16 o0, o1, lacc;
    #pragma unroll
    for (int q = 0; q < 16; ++q) { o0[q] = 0.f; o1[q] = 0.f; lacc[q] = 0.f; }
    U4B8 ones;
    ones.u[0] = 0x3F803F80u; ones.u[1] = 0x3F803F80u;
    ones.u[2] = 0x3F803F80u; ones.u[3] = 0x3F803F80u;

    int fq0 = (l31 ^ (l31 >> 3)) & 7;
    int fq1 = ((32 + l31) ^ ((32 + l31) >> 3)) & 7;

    #pragma unroll 1
    for (int it = 0; it < 6; ++it) {
        __syncthreads();
        #pragma unroll
        for (int i = 0; i < 4; ++i) {
            gld16(Kt + i * 2048, &Ks[(tid + i * 256) * 8]);
            gld16(Vtt + i * 2048, &Vts[(tid + i * 256) * 8]);
        }
        Kt += 8192; Vtt += 8192;
        __syncthreads();

        uint pkA[32];
        #pragma unroll
        for (int hf = 0; hf < 2; ++hf) {
            f32x16 s0, s1;
            #pragma unroll
            for (int q = 0; q < 16; ++q) { s0[q] = 0.f; s1[q] = 0.f; }
            int r0 = hf * 64 + l31, r1 = r0 + 32;
            #pragma unroll
            for (int kc = 0; kc < 4; ++kc) {
                int ch = 2 * kc + h;
                bf16x8 k0 = ld8(&Ks[r0 * 64 + ((ch ^ fq0) << 3)]);
                bf16x8 k1 = ld8(&Ks[r1 * 64 + ((ch ^ fq1) << 3)]);
                s0 = __builtin_amdgcn_mfma_f32_32x32x16_bf16(k0, qf[kc], s0, 0, 0, 0);
                s1 = __builtin_amdgcn_mfma_f32_32x32x16_bf16(k1, qf[kc], s1, 0, 0, 0);
            }
            #pragma unroll
            for (int u = 0; u < 8; ++u)
                pkA[hf * 16 + u] = cvtpk(exp2f(s0[2 * u]), exp2f(s0[2 * u + 1]));
            #pragma unroll
            for (int u = 0; u < 8; ++u)
                pkA[hf * 16 + 8 + u] = cvtpk(exp2f(s1[2 * u]), exp2f(s1[2 * u + 1]));
        }

        // PV + row-sum: A = P (regs), B = V^T / ones; chunks of 16 keys
        #pragma unroll
        for (int kc2 = 0; kc2 < 8; ++kc2) {
            U4B8 pf;
            pf.u[0] = pkA[4 * kc2];     pf.u[1] = pkA[4 * kc2 + 1];
            pf.u[2] = pkA[4 * kc2 + 2]; pf.u[3] = pkA[4 * kc2 + 3];
            int ch = 2 * kc2 + h;       // 0..15
            bf16x8 v0f = ld8(&Vts[l31 * 128 + (((ch & 8) | ((ch & 7) ^ fq0)) << 3)]);
            bf16x8 v1f = ld8(&Vts[(32 + l31) * 128 + (((ch & 8) | ((ch & 7) ^ fq1)) << 3)]);
            o0 = __builtin_amdgcn_mfma_f32_32x32x16_bf16(pf.v, v0f, o0, 0, 0, 0);
            o1 = __builtin_amdgcn_mfma_f32_32x32x16_bf16(pf.v, v1f, o1, 0, 0, 0);
            lacc = __builtin_amdgcn_mfma_f32_32x32x16_bf16(pf.v, ones.v, lacc, 0, 0, 0);
        }
    }

    // epilogue: atomic-accumulate partial O and l (order-independent sums)
    #pragma unroll
    for (int q = 0; q < 16; ++q) {
        int qrow = (q & 3) + 8 * (q >> 2) + 4 * h;
        int t = q0 + qrow;
        size_t base = ((size_t)b * TN + t) * Dd + hh * 64;
        unsafeAtomicAdd(&OP[base + l31], o0[q]);
        unsafeAtomicAdd(&OP[base + 32 + l31], o1[q]);
    }
    if (l31 == 0) {
        #pragma unroll
        for (int u = 0; u < 16; ++u) {
            int qrow = (u & 3) + 8 * (u >> 2) + 4 * h;
            unsafeAtomicAdd(&Sml[(size_t)bh * TN + q0 + qrow], lacc[u]);
        }
    }
}

// ---- kernel 6: output projection — double-buffered LDS, 8 stages x 32 din,
// XOR-swizzled M tile, split-bf16 MFMA, single OP read + 1/l scale ----
__global__ __launch_bounds__(256) void k_out(
        const float* __restrict__ OP, const float* __restrict__ Sml,
        const float* __restrict__ Wo, const float* __restrict__ bo,
        float* __restrict__ out) {
    __shared__ __align__(16) ushort Ms[2][64][64];   // [buf][t][8 chunks: hi 0-3, lo 4-7]
    __shared__ float invsh[64 * 4];
    int nd4 = blockIdx.x;              // 64-dout group (4)
    int R0 = blockIdx.y * 64;          // 64-token group (192)
    int b = R0 / TN;
    int tloc0 = R0 - b * TN;
    int tid = threadIdx.x, wave = tid >> 6, lane = tid & 63;
    int l31 = lane & 31, h = lane >> 5;
    int wt = wave & 1, wd = wave >> 1;
    {
        int hd = tid >> 6, t = tid & 63;
        invsh[t * 4 + hd] = 1.f / Sml[(size_t)(b * 4 + hd) * TN + tloc0 + t];
    }
    int dout = nd4 * 64 + wd * 32 + l31;
    float bb = bo[dout];
    const float* wrow = &Wo[(size_t)dout * 256];
    int st_t = tid >> 2, st_c = tid & 3;
    int fst = (st_t ^ (st_t >> 3)) & 7;
    size_t gbase = ((size_t)(b * TN + tloc0 + st_t)) * 256 + st_c * 8;
    int trow = wt * 32 + l31;
    int ftr = (trow ^ (trow >> 3)) & 7;
    f32x16 acc;
    #pragma unroll
    for (int q = 0; q < 16; ++q) acc[q] = 0.f;

    auto stage_load = [&](int st, int buf) {
        size_t ob = gbase + (size_t)st * 32;
        float4 x0 = *(const float4*)&OP[ob];
        float4 x1 = *(const float4*)&OP[ob + 4];
        float s = invsh[st_t * 4 + (st >> 1)];
        float m0 = x0.x * s, m1 = x0.y * s, m2 = x0.z * s, m3 = x0.w * s;
        float m4 = x1.x * s, m5 = x1.y * s, m6 = x1.z * s, m7 = x1.w * s;
        uint4 hi = { trunc_pk(m0, m1), trunc_pk(m2, m3),
                     trunc_pk(m4, m5), trunc_pk(m6, m7) };
        uint4 lo = { trunc_pk(m0 - hi_f(m0), m1 - hi_f(m1)),
                     trunc_pk(m2 - hi_f(m2), m3 - hi_f(m3)),
                     trunc_pk(m4 - hi_f(m4), m5 - hi_f(m5)),
                     trunc_pk(m6 - hi_f(m6), m7 - hi_f(m7)) };
        *(uint4*)&Ms[buf][st_t][(st_c ^ fst) * 8] = hi;
        *(uint4*)&Ms[buf][st_t][((4 + st_c) ^ fst) * 8] = lo;
    };

    __syncthreads();            // invsh visible
    stage_load(0, 0);
    #pragma unroll 1
    for (int st = 0; st < 8; ++st) {
        __syncthreads();        // buf[st&1] visible; previous reads complete
        if (st < 7) stage_load(st + 1, (st + 1) & 1);
        int buf = st & 1;
        #pragma unroll
        for (int kc = 0; kc < 2; ++kc) {
            bf16x8 ah = *(const bf16x8*)&Ms[buf][trow][((2 * kc + h) ^ ftr) * 8];
            bf16x8 al = *(const bf16x8*)&Ms[buf][trow][((4 + 2 * kc + h) ^ ftr) * 8];
            int din0 = st * 32 + kc * 16 + 8 * h;
            float4 w0 = *(const float4*)&wrow[din0];
            float4 w1 = *(const float4*)&wrow[din0 + 4];
            U4B8 wh, wl;
            wh.u[0] = trunc_pk(w0.x, w0.y); wh.u[1] = trunc_pk(w0.z, w0.w);
            wh.u[2] = trunc_pk(w1.x, w1.y); wh.u[3] = trunc_pk(w1.z, w1.w);
            wl.u[0] = trunc_pk(w0.x - hi_f(w0.x), w0.y - hi_f(w0.y));
            wl.u[1] = trunc_pk(w0.z - hi_f(w0.z), w0.w - hi_f(w0.w));
            wl.u[2] = trunc_pk(w1.x - hi_f(w1.x), w1.y - hi_f(w1.y));
            wl.u[3] = trunc_pk(w1.z - hi_f(w1.z), w1.w - hi_f(w1.w));
            acc = __builtin_amdgcn_mfma_f32_32x32x16_bf16(ah, wh.v, acc, 0, 0, 0);
            acc = __builtin_amdgcn_mfma_f32_32x32x16_bf16(al, wh.v, acc, 0, 0, 0);
            acc = __builtin_amdgcn_mfma_f32_32x32x16_bf16(ah, wl.v, acc, 0, 0, 0);
        }
    }
    #pragma unroll
    for (int u = 0; u < 16; ++u) {
        int tloc = tloc0 + wt * 32 + (u & 3) + 8 * (u >> 2) + 4 * h;
        int chunk = tloc >> 10, tt = tloc & 1023;
        out[(size_t)chunk * (Bsz * Nn * Dd) + ((size_t)(b * Nn + tt)) * Dd + dout] =
            acc[u] + bb;
    }
}

extern "C" void kernel_launch(void* const* d_in, const int* in_sizes, int n_in,
                              void* d_out, int out_size, void* d_ws, size_t ws_size,
                              hipStream_t stream) {
    const float* F0 = (const float*)d_in[0];
    const float* F1 = (const float*)d_in[1];
    const float* F2 = (const float*)d_in[2];
    const float* Wq = (const float*)d_in[3];
    const float* bq = (const float*)d_in[4];
    const float* Wk = (const float*)d_in[5];
    const float* bk = (const float*)d_in[6];
    const float* Wv = (const float*)d_in[7];
    const float* bv = (const float*)d_in[8];
    const float* Wo = (const float*)d_in[9];
    const float* bo = (const float*)d_in[10];
    float* ws = (float*)d_ws;
    float* out = (float*)d_out;

    int* idxp = (int*)(ws + IDX_OFF);
    uint* Xcb = (uint*)(ws + XCB_OFF);
    uint* Wct = (uint*)(ws + WCT_OFF);
    ushort* Qb16 = (ushort*)(ws + QB_OFF);
    ushort* Kb16 = (ushort*)(ws + KB_OFF);
    ushort* Vt16 = (ushort*)(ws + VT_OFF);
    float* OP = ws + OP_OFF;
    float* Sml = ws + SML_OFF;

    k_sal<<<384, 256, 0, stream>>>(F0, F1, F2, ws + SALP_OFF, OP);
    k_topk<<<Bsz, 256, 0, stream>>>(ws + SALP_OFF, idxp, Sml);
    k_gather<<<768, 256, 0, stream>>>(F0, F1, F2, Wq, Wk, Wv, idxp, Xcb, Wct);
    k_qkv<<<576, 256, 0, stream>>>((const ushort*)Xcb, (const ushort*)Wct,
                                   bq, bk, bv, Qb16, Kb16, Vt16);
    k_attn<<<1536, 256, 0, stream>>>(Qb16, Kb16, Vt16, OP, Sml);
    k_out<<<dim3(4, 192), 256, 0, stream>>>(OP, Sml, Wo, bo, out);
}